// Round 1
// baseline (725.388 us; speedup 1.0000x reference)
//
#include <hip/hip_runtime.h>
#include <stdint.h>
#include <stddef.h>

// ---------------- helpers ----------------
static __device__ __forceinline__ unsigned enc_min(float v) {
  unsigned u = __float_as_uint(v);
  return (u & 0x80000000u) ? ~u : (u | 0x80000000u);
}

// ---------------- degree count ----------------
__global__ void k_count(const int* __restrict__ edge, int E, int* __restrict__ cnt) {
  int e = blockIdx.x * blockDim.x + threadIdx.x;
  if (e < E) atomicAdd(&cnt[edge[E + e]], 1);  // dst = edge_index[1][e]
}

// ---------------- block inclusive scan (1024/block) ----------------
__global__ void k_scan1(const int* __restrict__ cnt, int N,
                        int* __restrict__ incl, int* __restrict__ bsum) {
  __shared__ int sm[1024];
  int tid = threadIdx.x;
  int i = blockIdx.x * 1024 + tid;
  int v = (i < N) ? cnt[i] : 0;
  sm[tid] = v;
  __syncthreads();
  for (int off = 1; off < 1024; off <<= 1) {
    int t = (tid >= off) ? sm[tid - off] : 0;
    __syncthreads();
    sm[tid] += t;
    __syncthreads();
  }
  if (i < N) incl[i] = sm[tid];
  if (tid == 1023) bsum[blockIdx.x] = sm[1023];
}

// ---------------- scan of block sums (nb <= 128) ----------------
__global__ void k_scan2(const int* __restrict__ bsum, int nb, int* __restrict__ boff) {
  __shared__ int sm[128];
  int tid = threadIdx.x;
  int v = (tid < nb) ? bsum[tid] : 0;
  sm[tid] = v;
  __syncthreads();
  for (int off = 1; off < 128; off <<= 1) {
    int t = (tid >= off) ? sm[tid - off] : 0;
    __syncthreads();
    sm[tid] += t;
    __syncthreads();
  }
  if (tid < nb) boff[tid] = sm[tid] - v;  // exclusive
}

// ---------------- row_ptr / cursor / dinv ----------------
__global__ void k_aux(const int* __restrict__ cnt, const int* __restrict__ incl,
                      const int* __restrict__ boff, int N, int E,
                      int* __restrict__ row_ptr, int* __restrict__ cursor,
                      float* __restrict__ dinv) {
  int i = blockIdx.x * blockDim.x + threadIdx.x;
  if (i < N) {
    int rp = incl[i] - cnt[i] + boff[i >> 10];
    row_ptr[i] = rp;
    cursor[i] = rp;
    dinv[i] = 1.0f / sqrtf((float)(cnt[i] + 1));  // +1 self-loop; deg>=1 always
  } else if (i == N) {
    row_ptr[N] = E;
  }
}

// ---------------- CSR fill (bucket by dst, store src) ----------------
__global__ void k_fill(const int* __restrict__ edge, int E,
                       int* __restrict__ cursor, int* __restrict__ srcs) {
  int e = blockIdx.x * blockDim.x + threadIdx.x;
  if (e < E) {
    int s = edge[e];
    int d = edge[E + e];
    int pos = atomicAdd(&cursor[d], 1);
    srcs[pos] = s;
  }
}

// ---------------- GEMM: P = (A @ W) * dinv[row];  K=128, Nc=64*G ----------------
// block: 256 threads (16x16), tile 64 rows x (64*G) cols, K chunked by 32.
template <int G>
__global__ __launch_bounds__(256) void k_gemm(const float* __restrict__ A,
                                              const float* __restrict__ W,
                                              const float* __restrict__ dinv,
                                              float* __restrict__ P, int M) {
  const int K = 128;
  const int Nc = 64 * G;
  __shared__ float As[32][68];           // As[k][m], transposed A tile
  __shared__ float Bs[32][64 * G + 4];   // Bs[k][n]
  int tid = threadIdx.x;
  int tx = tid & 15, ty = tid >> 4;
  int m0 = blockIdx.x * 64;
  float acc[G][4][4];
#pragma unroll
  for (int g = 0; g < G; ++g)
#pragma unroll
    for (int i = 0; i < 4; ++i)
#pragma unroll
      for (int j = 0; j < 4; ++j) acc[g][i][j] = 0.f;

  for (int kc = 0; kc < K; kc += 32) {
#pragma unroll
    for (int q = 0; q < 2; ++q) {
      int f = q * 256 + tid;  // 0..511 -> 64 rows x 8 float4
      int m = f >> 3, k4 = f & 7;
      int row = m0 + m;
      if (row >= M) row = M - 1;  // clamp; garbage rows never stored
      float4 v = *(const float4*)&A[(size_t)row * K + kc + k4 * 4];
      As[k4 * 4 + 0][m] = v.x;
      As[k4 * 4 + 1][m] = v.y;
      As[k4 * 4 + 2][m] = v.z;
      As[k4 * 4 + 3][m] = v.w;
    }
#pragma unroll
    for (int q = 0; q < 2 * G; ++q) {
      int f = q * 256 + tid;  // 32 rows x 16G float4
      int kk = f / (16 * G), n4 = f % (16 * G);
      float4 v = *(const float4*)&W[(size_t)(kc + kk) * Nc + n4 * 4];
      *(float4*)&Bs[kk][n4 * 4] = v;
    }
    __syncthreads();
#pragma unroll
    for (int k = 0; k < 32; ++k) {
      float4 a4 = *(const float4*)&As[k][ty * 4];
      float av[4] = {a4.x, a4.y, a4.z, a4.w};
#pragma unroll
      for (int g = 0; g < G; ++g) {
        float4 b4 = *(const float4*)&Bs[k][g * 64 + tx * 4];
        float bv[4] = {b4.x, b4.y, b4.z, b4.w};
#pragma unroll
        for (int i = 0; i < 4; ++i)
#pragma unroll
          for (int j = 0; j < 4; ++j) acc[g][i][j] = fmaf(av[i], bv[j], acc[g][i][j]);
      }
    }
    __syncthreads();
  }
#pragma unroll
  for (int i = 0; i < 4; ++i) {
    int row = m0 + ty * 4 + i;
    if (row < M) {
      float dv = dinv[row];
#pragma unroll
      for (int g = 0; g < G; ++g) {
        float4 o;
        o.x = acc[g][i][0] * dv;
        o.y = acc[g][i][1] * dv;
        o.z = acc[g][i][2] * dv;
        o.w = acc[g][i][3] * dv;
        *(float4*)&P[(size_t)row * Nc + g * 64 + tx * 4] = o;
      }
    }
  }
}

// ---------------- aggregation: Hout[i] = act(dinv[i]*(P[i] + sum P[src]) + b) ----------------
// one block per node, one thread per channel (blockDim.x == C)
__global__ void k_agg(const float* __restrict__ P, const int* __restrict__ row_ptr,
                      const int* __restrict__ srcs, const float* __restrict__ dinv,
                      const float* __restrict__ bias, float* __restrict__ Hout,
                      int C, int relu) {
  __shared__ int sidx[128];
  int i = blockIdx.x;
  int c = threadIdx.x;
  float acc = P[(size_t)i * C + c];  // self-loop term
  int start = row_ptr[i], end = row_ptr[i + 1];
  for (int j0 = start; j0 < end; j0 += blockDim.x) {
    int take = min((int)blockDim.x, end - j0);
    if (c < take) sidx[c] = srcs[j0 + c];
    __syncthreads();
    int t = 0;
    for (; t + 4 <= take; t += 4) {
      float v0 = P[(size_t)sidx[t + 0] * C + c];
      float v1 = P[(size_t)sidx[t + 1] * C + c];
      float v2 = P[(size_t)sidx[t + 2] * C + c];
      float v3 = P[(size_t)sidx[t + 3] * C + c];
      acc += v0;
      acc += v1;
      acc += v2;
      acc += v3;
    }
    for (; t < take; ++t) acc += P[(size_t)sidx[t] * C + c];
    __syncthreads();
  }
  float v = dinv[i] * acc + bias[c];
  if (relu) v = fmaxf(v, 0.0f);
  Hout[(size_t)i * C + c] = v;
}

// ---------------- min pool over nodes ----------------
__global__ void k_minpool(const float* __restrict__ H, int N, unsigned* __restrict__ minenc) {
  __shared__ float sm[256];
  int tid = threadIdx.x;
  int c = tid & 63;
  int r = (blockIdx.x * blockDim.x + tid) >> 6;
  int stride = (gridDim.x * blockDim.x) >> 6;
  float mn = 3.402823466e38f;
  for (; r < N; r += stride) mn = fminf(mn, H[(size_t)r * 64 + c]);
  sm[tid] = mn;
  __syncthreads();
  if (tid < 64) {
    mn = fminf(fminf(sm[tid], sm[tid + 64]), fminf(sm[tid + 128], sm[tid + 192]));
    atomicMin(&minenc[c], enc_min(mn));
  }
}

__global__ void k_decode(const unsigned* __restrict__ minenc, float* __restrict__ out) {
  int c = threadIdx.x;
  unsigned k = minenc[c];
  unsigned u = (k & 0x80000000u) ? (k & 0x7FFFFFFFu) : ~k;
  out[c] = __uint_as_float(u);
}

// ---------------- launch ----------------
extern "C" void kernel_launch(void* const* d_in, const int* in_sizes, int n_in,
                              void* d_out, int out_size, void* d_ws, size_t ws_size,
                              hipStream_t stream) {
  const float* X  = (const float*)d_in[0];
  const int* edge = (const int*)d_in[1];
  const float* W1 = (const float*)d_in[2];
  const float* b1 = (const float*)d_in[3];
  const float* W2 = (const float*)d_in[4];
  const float* b2 = (const float*)d_in[5];
  const float* W3 = (const float*)d_in[6];
  const float* b3 = (const float*)d_in[7];
  float* out = (float*)d_out;

  const int IN_CH = 128;
  int N = in_sizes[0] / IN_CH;
  int E = in_sizes[1] / 2;

  char* ws = (char*)d_ws;
  size_t off = 0;
  auto alloc = [&](size_t bytes) {
    void* p = ws + off;
    off = (off + bytes + 255) & ~(size_t)255;
    return p;
  };
  float* P       = (float*)alloc((size_t)N * 128 * 4);  // 51.2 MB
  float* H       = (float*)alloc((size_t)N * 128 * 4);  // 51.2 MB
  int* srcs      = (int*)alloc((size_t)E * 4);          // 6.4 MB
  int* cnt       = (int*)alloc((size_t)N * 4);
  int* incl      = (int*)alloc((size_t)N * 4);
  int* row_ptr   = (int*)alloc((size_t)(N + 1) * 4);
  int* cursor    = (int*)alloc((size_t)N * 4);
  float* dinv    = (float*)alloc((size_t)N * 4);
  int* bsum      = (int*)alloc(1024);
  int* boff      = (int*)alloc(1024);
  unsigned* minenc = (unsigned*)alloc(256);

  hipMemsetAsync(cnt, 0, (size_t)N * 4, stream);
  hipMemsetAsync(minenc, 0xFF, 64 * 4, stream);  // encoded +max

  int nb = (N + 1023) / 1024;  // 98 for N=100000 (<=128 required by k_scan2)
  k_count<<<(E + 255) / 256, 256, 0, stream>>>(edge, E, cnt);
  k_scan1<<<nb, 1024, 0, stream>>>(cnt, N, incl, bsum);
  k_scan2<<<1, 128, 0, stream>>>(bsum, nb, boff);
  k_aux<<<(N + 256) / 256, 256, 0, stream>>>(cnt, incl, boff, N, E, row_ptr, cursor, dinv);
  k_fill<<<(E + 255) / 256, 256, 0, stream>>>(edge, E, cursor, srcs);

  int gx = (N + 63) / 64;
  // layer 1: P = (X @ W1)*dinv ; H = relu(dinv*(P+gather) + b1)
  k_gemm<2><<<gx, 256, 0, stream>>>(X, W1, dinv, P, N);
  k_agg<<<N, 128, 0, stream>>>(P, row_ptr, srcs, dinv, b1, H, 128, 1);
  // layer 2
  k_gemm<2><<<gx, 256, 0, stream>>>(H, W2, dinv, P, N);
  k_agg<<<N, 128, 0, stream>>>(P, row_ptr, srcs, dinv, b2, H, 128, 1);
  // layer 3 (64 ch, no relu)
  k_gemm<1><<<gx, 256, 0, stream>>>(H, W3, dinv, P, N);
  k_agg<<<N, 64, 0, stream>>>(P, row_ptr, srcs, dinv, b3, H, 64, 0);
  // min pool -> out[64]
  k_minpool<<<512, 256, 0, stream>>>(H, N, minenc);
  k_decode<<<1, 64, 0, stream>>>(minenc, out);
}

// Round 2
// 671.321 us; speedup vs baseline: 1.0805x; 1.0805x over previous
//
#include <hip/hip_runtime.h>
#include <stdint.h>
#include <stddef.h>

// ---------------- helpers ----------------
static __device__ __forceinline__ unsigned enc_min(float v) {
  unsigned u = __float_as_uint(v);
  return (u & 0x80000000u) ? ~u : (u | 0x80000000u);
}

// ---------------- degree count, XCD-binned ----------------
// block b handles dst range (b&7); grid-strides over all edges within its
// group. Heuristic: blockIdx%8 == XCD id, so each cnt slice stays in ONE
// XCD's L2 and lines fill completely before writeback. Correct regardless
// of the mapping (each edge counted exactly once by exactly one group).
__global__ void k_count(const int* __restrict__ edge, int E, int N, int* __restrict__ cnt) {
  int grp = blockIdx.x & 7;
  int bslot = blockIdx.x >> 3;
  int nslot = gridDim.x >> 3;
  int lo = (int)(((long long)N * grp) >> 3);
  int hi = (int)(((long long)N * (grp + 1)) >> 3);
  for (int e = bslot * blockDim.x + threadIdx.x; e < E; e += nslot * blockDim.x) {
    int d = edge[E + e];
    if (d >= lo && d < hi) atomicAdd(&cnt[d], 1);
  }
}

// ---------------- block inclusive scan (1024/block) ----------------
__global__ void k_scan1(const int* __restrict__ cnt, int N,
                        int* __restrict__ incl, int* __restrict__ bsum) {
  __shared__ int sm[1024];
  int tid = threadIdx.x;
  int i = blockIdx.x * 1024 + tid;
  int v = (i < N) ? cnt[i] : 0;
  sm[tid] = v;
  __syncthreads();
  for (int off = 1; off < 1024; off <<= 1) {
    int t = (tid >= off) ? sm[tid - off] : 0;
    __syncthreads();
    sm[tid] += t;
    __syncthreads();
  }
  if (i < N) incl[i] = sm[tid];
  if (tid == 1023) bsum[blockIdx.x] = sm[1023];
}

// ---------------- scan of block sums (nb <= 128) ----------------
__global__ void k_scan2(const int* __restrict__ bsum, int nb, int* __restrict__ boff) {
  __shared__ int sm[128];
  int tid = threadIdx.x;
  int v = (tid < nb) ? bsum[tid] : 0;
  sm[tid] = v;
  __syncthreads();
  for (int off = 1; off < 128; off <<= 1) {
    int t = (tid >= off) ? sm[tid - off] : 0;
    __syncthreads();
    sm[tid] += t;
    __syncthreads();
  }
  if (tid < nb) boff[tid] = sm[tid] - v;  // exclusive
}

// ---------------- row_ptr / cursor / dinv ----------------
__global__ void k_aux(const int* __restrict__ cnt, const int* __restrict__ incl,
                      const int* __restrict__ boff, int N, int E,
                      int* __restrict__ row_ptr, int* __restrict__ cursor,
                      float* __restrict__ dinv) {
  int i = blockIdx.x * blockDim.x + threadIdx.x;
  if (i < N) {
    int rp = incl[i] - cnt[i] + boff[i >> 10];
    row_ptr[i] = rp;
    cursor[i] = rp;
    dinv[i] = 1.0f / sqrtf((float)(cnt[i] + 1));  // +1 self-loop; deg>=1 always
  } else if (i == N) {
    row_ptr[N] = E;
  }
}

// ---------------- CSR fill (bucket by dst, store src), XCD-binned ----------------
// Same %8 grouping as k_count: all scattered writes to a srcs/cursor slice
// come from one XCD, so 64B lines fill in its L2 instead of generating one
// partial-line HBM writeback per 4B store (was 105 MB WRITE_SIZE).
__global__ void k_fill(const int* __restrict__ edge, int E, int N,
                       int* __restrict__ cursor, int* __restrict__ srcs) {
  int grp = blockIdx.x & 7;
  int bslot = blockIdx.x >> 3;
  int nslot = gridDim.x >> 3;
  int lo = (int)(((long long)N * grp) >> 3);
  int hi = (int)(((long long)N * (grp + 1)) >> 3);
  for (int e = bslot * blockDim.x + threadIdx.x; e < E; e += nslot * blockDim.x) {
    int d = edge[E + e];
    if (d >= lo && d < hi) {
      int s = edge[e];
      int pos = atomicAdd(&cursor[d], 1);
      srcs[pos] = s;
    }
  }
}

// ---------------- GEMM: P = (A @ W) * dinv[row];  K=128, Nc=64*G ----------------
// block: 256 threads (16x16), tile 64 rows x (64*G) cols, K chunked by 32.
template <int G>
__global__ __launch_bounds__(256) void k_gemm(const float* __restrict__ A,
                                              const float* __restrict__ W,
                                              const float* __restrict__ dinv,
                                              float* __restrict__ P, int M) {
  const int K = 128;
  const int Nc = 64 * G;
  __shared__ float As[32][68];           // As[k][m], transposed A tile
  __shared__ float Bs[32][64 * G + 4];   // Bs[k][n]
  int tid = threadIdx.x;
  int tx = tid & 15, ty = tid >> 4;
  int m0 = blockIdx.x * 64;
  float acc[G][4][4];
#pragma unroll
  for (int g = 0; g < G; ++g)
#pragma unroll
    for (int i = 0; i < 4; ++i)
#pragma unroll
      for (int j = 0; j < 4; ++j) acc[g][i][j] = 0.f;

  for (int kc = 0; kc < K; kc += 32) {
#pragma unroll
    for (int q = 0; q < 2; ++q) {
      int f = q * 256 + tid;  // 0..511 -> 64 rows x 8 float4
      int m = f >> 3, k4 = f & 7;
      int row = m0 + m;
      if (row >= M) row = M - 1;  // clamp; garbage rows never stored
      float4 v = *(const float4*)&A[(size_t)row * K + kc + k4 * 4];
      As[k4 * 4 + 0][m] = v.x;
      As[k4 * 4 + 1][m] = v.y;
      As[k4 * 4 + 2][m] = v.z;
      As[k4 * 4 + 3][m] = v.w;
    }
#pragma unroll
    for (int q = 0; q < 2 * G; ++q) {
      int f = q * 256 + tid;  // 32 rows x 16G float4
      int kk = f / (16 * G), n4 = f % (16 * G);
      float4 v = *(const float4*)&W[(size_t)(kc + kk) * Nc + n4 * 4];
      *(float4*)&Bs[kk][n4 * 4] = v;
    }
    __syncthreads();
#pragma unroll
    for (int k = 0; k < 32; ++k) {
      float4 a4 = *(const float4*)&As[k][ty * 4];
      float av[4] = {a4.x, a4.y, a4.z, a4.w};
#pragma unroll
      for (int g = 0; g < G; ++g) {
        float4 b4 = *(const float4*)&Bs[k][g * 64 + tx * 4];
        float bv[4] = {b4.x, b4.y, b4.z, b4.w};
#pragma unroll
        for (int i = 0; i < 4; ++i)
#pragma unroll
          for (int j = 0; j < 4; ++j) acc[g][i][j] = fmaf(av[i], bv[j], acc[g][i][j]);
      }
    }
    __syncthreads();
  }
#pragma unroll
  for (int i = 0; i < 4; ++i) {
    int row = m0 + ty * 4 + i;
    if (row < M) {
      float dv = dinv[row];
#pragma unroll
      for (int g = 0; g < G; ++g) {
        float4 o;
        o.x = acc[g][i][0] * dv;
        o.y = acc[g][i][1] * dv;
        o.z = acc[g][i][2] * dv;
        o.w = acc[g][i][3] * dv;
        *(float4*)&P[(size_t)row * Nc + g * 64 + tx * 4] = o;
      }
    }
  }
}

// ---------------- aggregation: Hout[i] = act(dinv[i]*(P[i] + sum P[src]) + b) ----------------
// one block per node, one thread per channel (blockDim.x == C)
__global__ void k_agg(const float* __restrict__ P, const int* __restrict__ row_ptr,
                      const int* __restrict__ srcs, const float* __restrict__ dinv,
                      const float* __restrict__ bias, float* __restrict__ Hout,
                      int C, int relu) {
  __shared__ int sidx[128];
  int i = blockIdx.x;
  int c = threadIdx.x;
  float acc = P[(size_t)i * C + c];  // self-loop term
  int start = row_ptr[i], end = row_ptr[i + 1];
  for (int j0 = start; j0 < end; j0 += blockDim.x) {
    int take = min((int)blockDim.x, end - j0);
    if (c < take) sidx[c] = srcs[j0 + c];
    __syncthreads();
    int t = 0;
    for (; t + 4 <= take; t += 4) {
      float v0 = P[(size_t)sidx[t + 0] * C + c];
      float v1 = P[(size_t)sidx[t + 1] * C + c];
      float v2 = P[(size_t)sidx[t + 2] * C + c];
      float v3 = P[(size_t)sidx[t + 3] * C + c];
      acc += v0;
      acc += v1;
      acc += v2;
      acc += v3;
    }
    for (; t < take; ++t) acc += P[(size_t)sidx[t] * C + c];
    __syncthreads();
  }
  float v = dinv[i] * acc + bias[c];
  if (relu) v = fmaxf(v, 0.0f);
  Hout[(size_t)i * C + c] = v;
}

// ---------------- min pool over nodes ----------------
__global__ void k_minpool(const float* __restrict__ H, int N, unsigned* __restrict__ minenc) {
  __shared__ float sm[256];
  int tid = threadIdx.x;
  int c = tid & 63;
  int r = (blockIdx.x * blockDim.x + tid) >> 6;
  int stride = (gridDim.x * blockDim.x) >> 6;
  float mn = 3.402823466e38f;
  for (; r < N; r += stride) mn = fminf(mn, H[(size_t)r * 64 + c]);
  sm[tid] = mn;
  __syncthreads();
  if (tid < 64) {
    mn = fminf(fminf(sm[tid], sm[tid + 64]), fminf(sm[tid + 128], sm[tid + 192]));
    atomicMin(&minenc[c], enc_min(mn));
  }
}

__global__ void k_decode(const unsigned* __restrict__ minenc, float* __restrict__ out) {
  int c = threadIdx.x;
  unsigned k = minenc[c];
  unsigned u = (k & 0x80000000u) ? (k & 0x7FFFFFFFu) : ~k;
  out[c] = __uint_as_float(u);
}

// ---------------- launch ----------------
extern "C" void kernel_launch(void* const* d_in, const int* in_sizes, int n_in,
                              void* d_out, int out_size, void* d_ws, size_t ws_size,
                              hipStream_t stream) {
  const float* X  = (const float*)d_in[0];
  const int* edge = (const int*)d_in[1];
  const float* W1 = (const float*)d_in[2];
  const float* b1 = (const float*)d_in[3];
  const float* W2 = (const float*)d_in[4];
  const float* b2 = (const float*)d_in[5];
  const float* W3 = (const float*)d_in[6];
  const float* b3 = (const float*)d_in[7];
  float* out = (float*)d_out;

  const int IN_CH = 128;
  int N = in_sizes[0] / IN_CH;
  int E = in_sizes[1] / 2;

  char* ws = (char*)d_ws;
  size_t off = 0;
  auto alloc = [&](size_t bytes) {
    void* p = ws + off;
    off = (off + bytes + 255) & ~(size_t)255;
    return p;
  };
  float* P       = (float*)alloc((size_t)N * 128 * 4);  // 51.2 MB
  float* H       = (float*)alloc((size_t)N * 128 * 4);  // 51.2 MB
  int* srcs      = (int*)alloc((size_t)E * 4);          // 6.4 MB
  int* cnt       = (int*)alloc((size_t)N * 4);
  int* incl      = (int*)alloc((size_t)N * 4);
  int* row_ptr   = (int*)alloc((size_t)(N + 1) * 4);
  int* cursor    = (int*)alloc((size_t)N * 4);
  float* dinv    = (float*)alloc((size_t)N * 4);
  int* bsum      = (int*)alloc(1024);
  int* boff      = (int*)alloc(1024);
  unsigned* minenc = (unsigned*)alloc(256);

  hipMemsetAsync(cnt, 0, (size_t)N * 4, stream);
  hipMemsetAsync(minenc, 0xFF, 64 * 4, stream);  // encoded +max

  int nb = (N + 1023) / 1024;  // 98 for N=100000 (<=128 required by k_scan2)
  k_count<<<1024, 256, 0, stream>>>(edge, E, N, cnt);
  k_scan1<<<nb, 1024, 0, stream>>>(cnt, N, incl, bsum);
  k_scan2<<<1, 128, 0, stream>>>(bsum, nb, boff);
  k_aux<<<(N + 256) / 256, 256, 0, stream>>>(cnt, incl, boff, N, E, row_ptr, cursor, dinv);
  k_fill<<<1024, 256, 0, stream>>>(edge, E, N, cursor, srcs);

  int gx = (N + 63) / 64;
  // layer 1: P = (X @ W1)*dinv ; H = relu(dinv*(P+gather) + b1)
  k_gemm<2><<<gx, 256, 0, stream>>>(X, W1, dinv, P, N);
  k_agg<<<N, 128, 0, stream>>>(P, row_ptr, srcs, dinv, b1, H, 128, 1);
  // layer 2
  k_gemm<2><<<gx, 256, 0, stream>>>(H, W2, dinv, P, N);
  k_agg<<<N, 128, 0, stream>>>(P, row_ptr, srcs, dinv, b2, H, 128, 1);
  // layer 3 (64 ch, no relu)
  k_gemm<1><<<gx, 256, 0, stream>>>(H, W3, dinv, P, N);
  k_agg<<<N, 64, 0, stream>>>(P, row_ptr, srcs, dinv, b3, H, 64, 0);
  // min pool -> out[64]
  k_minpool<<<512, 256, 0, stream>>>(H, N, minenc);
  k_decode<<<1, 64, 0, stream>>>(minenc, out);
}

// Round 3
// 620.258 us; speedup vs baseline: 1.1695x; 1.0823x over previous
//
#include <hip/hip_runtime.h>
#include <stdint.h>
#include <stddef.h>

// ---------------- helpers ----------------
static __device__ __forceinline__ unsigned enc_min(float v) {
  unsigned u = __float_as_uint(v);
  return (u & 0x80000000u) ? ~u : (u | 0x80000000u);
}
static __device__ __forceinline__ unsigned short f2bf(float f) {
  // round-to-nearest-even; inputs are finite normals here
  unsigned u = __float_as_uint(f);
  u += 0x7fffu + ((u >> 16) & 1u);
  return (unsigned short)(u >> 16);
}
static __device__ __forceinline__ float bf2f(unsigned short b) {
  return __uint_as_float(((unsigned)b) << 16);
}

// ---------------- degree count, XCD-binned ----------------
__global__ void k_count(const int* __restrict__ edge, int E, int N, int* __restrict__ cnt) {
  int grp = blockIdx.x & 7;
  int bslot = blockIdx.x >> 3;
  int nslot = gridDim.x >> 3;
  int lo = (int)(((long long)N * grp) >> 3);
  int hi = (int)(((long long)N * (grp + 1)) >> 3);
  for (int e = bslot * blockDim.x + threadIdx.x; e < E; e += nslot * blockDim.x) {
    int d = edge[E + e];
    if (d >= lo && d < hi) atomicAdd(&cnt[d], 1);
  }
}

// ---------------- block inclusive scan (1024/block) ----------------
__global__ void k_scan1(const int* __restrict__ cnt, int N,
                        int* __restrict__ incl, int* __restrict__ bsum) {
  __shared__ int sm[1024];
  int tid = threadIdx.x;
  int i = blockIdx.x * 1024 + tid;
  int v = (i < N) ? cnt[i] : 0;
  sm[tid] = v;
  __syncthreads();
  for (int off = 1; off < 1024; off <<= 1) {
    int t = (tid >= off) ? sm[tid - off] : 0;
    __syncthreads();
    sm[tid] += t;
    __syncthreads();
  }
  if (i < N) incl[i] = sm[tid];
  if (tid == 1023) bsum[blockIdx.x] = sm[1023];
}

// ---------------- scan of block sums (nb <= 128) ----------------
__global__ void k_scan2(const int* __restrict__ bsum, int nb, int* __restrict__ boff) {
  __shared__ int sm[128];
  int tid = threadIdx.x;
  int v = (tid < nb) ? bsum[tid] : 0;
  sm[tid] = v;
  __syncthreads();
  for (int off = 1; off < 128; off <<= 1) {
    int t = (tid >= off) ? sm[tid - off] : 0;
    __syncthreads();
    sm[tid] += t;
    __syncthreads();
  }
  if (tid < nb) boff[tid] = sm[tid] - v;  // exclusive
}

// ---------------- row_ptr / cursor / dinv ----------------
__global__ void k_aux(const int* __restrict__ cnt, const int* __restrict__ incl,
                      const int* __restrict__ boff, int N, int E,
                      int* __restrict__ row_ptr, int* __restrict__ cursor,
                      float* __restrict__ dinv) {
  int i = blockIdx.x * blockDim.x + threadIdx.x;
  if (i < N) {
    int rp = incl[i] - cnt[i] + boff[i >> 10];
    row_ptr[i] = rp;
    cursor[i] = rp;
    dinv[i] = 1.0f / sqrtf((float)(cnt[i] + 1));  // +1 self-loop; deg>=1 always
  } else if (i == N) {
    row_ptr[N] = E;
  }
}

// ---------------- CSR fill (bucket by dst, store src), XCD-binned ----------------
__global__ void k_fill(const int* __restrict__ edge, int E, int N,
                       int* __restrict__ cursor, int* __restrict__ srcs) {
  int grp = blockIdx.x & 7;
  int bslot = blockIdx.x >> 3;
  int nslot = gridDim.x >> 3;
  int lo = (int)(((long long)N * grp) >> 3);
  int hi = (int)(((long long)N * (grp + 1)) >> 3);
  for (int e = bslot * blockDim.x + threadIdx.x; e < E; e += nslot * blockDim.x) {
    int d = edge[E + e];
    if (d >= lo && d < hi) {
      int s = edge[e];
      int pos = atomicAdd(&cursor[d], 1);
      srcs[pos] = s;
    }
  }
}

// ---------------- GEMM: P = bf16((A @ W) * dinv[row]);  K=128, Nc=64*G ----------------
// block: 256 threads (16x16), tile 64 rows x (64*G) cols, K chunked by 32.
template <int G>
__global__ __launch_bounds__(256) void k_gemm(const float* __restrict__ A,
                                              const float* __restrict__ W,
                                              const float* __restrict__ dinv,
                                              unsigned short* __restrict__ P, int M) {
  const int K = 128;
  const int Nc = 64 * G;
  __shared__ float As[32][68];           // As[k][m], transposed A tile
  __shared__ float Bs[32][64 * G + 4];   // Bs[k][n]
  int tid = threadIdx.x;
  int tx = tid & 15, ty = tid >> 4;
  int m0 = blockIdx.x * 64;
  float acc[G][4][4];
#pragma unroll
  for (int g = 0; g < G; ++g)
#pragma unroll
    for (int i = 0; i < 4; ++i)
#pragma unroll
      for (int j = 0; j < 4; ++j) acc[g][i][j] = 0.f;

  for (int kc = 0; kc < K; kc += 32) {
#pragma unroll
    for (int q = 0; q < 2; ++q) {
      int f = q * 256 + tid;  // 0..511 -> 64 rows x 8 float4
      int m = f >> 3, k4 = f & 7;
      int row = m0 + m;
      if (row >= M) row = M - 1;  // clamp; garbage rows never stored
      float4 v = *(const float4*)&A[(size_t)row * K + kc + k4 * 4];
      As[k4 * 4 + 0][m] = v.x;
      As[k4 * 4 + 1][m] = v.y;
      As[k4 * 4 + 2][m] = v.z;
      As[k4 * 4 + 3][m] = v.w;
    }
#pragma unroll
    for (int q = 0; q < 2 * G; ++q) {
      int f = q * 256 + tid;  // 32 rows x 16G float4
      int kk = f / (16 * G), n4 = f % (16 * G);
      float4 v = *(const float4*)&W[(size_t)(kc + kk) * Nc + n4 * 4];
      *(float4*)&Bs[kk][n4 * 4] = v;
    }
    __syncthreads();
#pragma unroll
    for (int k = 0; k < 32; ++k) {
      float4 a4 = *(const float4*)&As[k][ty * 4];
      float av[4] = {a4.x, a4.y, a4.z, a4.w};
#pragma unroll
      for (int g = 0; g < G; ++g) {
        float4 b4 = *(const float4*)&Bs[k][g * 64 + tx * 4];
        float bv[4] = {b4.x, b4.y, b4.z, b4.w};
#pragma unroll
        for (int i = 0; i < 4; ++i)
#pragma unroll
          for (int j = 0; j < 4; ++j) acc[g][i][j] = fmaf(av[i], bv[j], acc[g][i][j]);
      }
    }
    __syncthreads();
  }
#pragma unroll
  for (int i = 0; i < 4; ++i) {
    int row = m0 + ty * 4 + i;
    if (row < M) {
      float dv = dinv[row];
#pragma unroll
      for (int g = 0; g < G; ++g) {
        uint2 o;
        o.x = (unsigned)f2bf(acc[g][i][0] * dv) | ((unsigned)f2bf(acc[g][i][1] * dv) << 16);
        o.y = (unsigned)f2bf(acc[g][i][2] * dv) | ((unsigned)f2bf(acc[g][i][3] * dv) << 16);
        *(uint2*)&P[(size_t)row * Nc + g * 64 + tx * 4] = o;
      }
    }
  }
}

// ---------------- aggregation: Hout[i] = act(dinv[i]*(P[i] + sum P[src]) + b) ----------------
// one block per node, one thread per channel (blockDim.x == C); P is bf16,
// accumulation in fp32 (only error source: one RNE rounding of P elements)
template <int C, int RELU>
__global__ void k_agg(const unsigned short* __restrict__ P, const int* __restrict__ row_ptr,
                      const int* __restrict__ srcs, const float* __restrict__ dinv,
                      const float* __restrict__ bias, float* __restrict__ Hout) {
  __shared__ int sidx[C];
  int i = blockIdx.x;
  int c = threadIdx.x;
  float acc = bf2f(P[(size_t)i * C + c]);  // self-loop term
  int start = row_ptr[i], end = row_ptr[i + 1];
  for (int j0 = start; j0 < end; j0 += C) {
    int take = min(C, end - j0);
    if (c < take) sidx[c] = srcs[j0 + c];
    __syncthreads();
    int t = 0;
    for (; t + 4 <= take; t += 4) {
      float v0 = bf2f(P[(size_t)sidx[t + 0] * C + c]);
      float v1 = bf2f(P[(size_t)sidx[t + 1] * C + c]);
      float v2 = bf2f(P[(size_t)sidx[t + 2] * C + c]);
      float v3 = bf2f(P[(size_t)sidx[t + 3] * C + c]);
      acc += v0;
      acc += v1;
      acc += v2;
      acc += v3;
    }
    for (; t < take; ++t) acc += bf2f(P[(size_t)sidx[t] * C + c]);
    __syncthreads();
  }
  float v = dinv[i] * acc + bias[c];
  if (RELU) v = fmaxf(v, 0.0f);
  Hout[(size_t)i * C + c] = v;
}

// ---------------- min pool over nodes ----------------
__global__ void k_minpool(const float* __restrict__ H, int N, unsigned* __restrict__ minenc) {
  __shared__ float sm[256];
  int tid = threadIdx.x;
  int c = tid & 63;
  int r = (blockIdx.x * blockDim.x + tid) >> 6;
  int stride = (gridDim.x * blockDim.x) >> 6;
  float mn = 3.402823466e38f;
  for (; r < N; r += stride) mn = fminf(mn, H[(size_t)r * 64 + c]);
  sm[tid] = mn;
  __syncthreads();
  if (tid < 64) {
    mn = fminf(fminf(sm[tid], sm[tid + 64]), fminf(sm[tid + 128], sm[tid + 192]));
    atomicMin(&minenc[c], enc_min(mn));
  }
}

__global__ void k_decode(const unsigned* __restrict__ minenc, float* __restrict__ out) {
  int c = threadIdx.x;
  unsigned k = minenc[c];
  unsigned u = (k & 0x80000000u) ? (k & 0x7FFFFFFFu) : ~k;
  out[c] = __uint_as_float(u);
}

// ---------------- launch ----------------
extern "C" void kernel_launch(void* const* d_in, const int* in_sizes, int n_in,
                              void* d_out, int out_size, void* d_ws, size_t ws_size,
                              hipStream_t stream) {
  const float* X  = (const float*)d_in[0];
  const int* edge = (const int*)d_in[1];
  const float* W1 = (const float*)d_in[2];
  const float* b1 = (const float*)d_in[3];
  const float* W2 = (const float*)d_in[4];
  const float* b2 = (const float*)d_in[5];
  const float* W3 = (const float*)d_in[6];
  const float* b3 = (const float*)d_in[7];
  float* out = (float*)d_out;

  const int IN_CH = 128;
  int N = in_sizes[0] / IN_CH;
  int E = in_sizes[1] / 2;

  char* ws = (char*)d_ws;
  size_t off = 0;
  auto alloc = [&](size_t bytes) {
    void* p = ws + off;
    off = (off + bytes + 255) & ~(size_t)255;
    return p;
  };
  unsigned short* P = (unsigned short*)alloc((size_t)N * 128 * 2);  // 25.6 MB bf16
  float* H       = (float*)alloc((size_t)N * 128 * 4);              // 51.2 MB
  int* srcs      = (int*)alloc((size_t)E * 4);                      // 6.4 MB
  int* cnt       = (int*)alloc((size_t)N * 4);
  int* incl      = (int*)alloc((size_t)N * 4);
  int* row_ptr   = (int*)alloc((size_t)(N + 1) * 4);
  int* cursor    = (int*)alloc((size_t)N * 4);
  float* dinv    = (float*)alloc((size_t)N * 4);
  int* bsum      = (int*)alloc(1024);
  int* boff      = (int*)alloc(1024);
  unsigned* minenc = (unsigned*)alloc(256);

  hipMemsetAsync(cnt, 0, (size_t)N * 4, stream);
  hipMemsetAsync(minenc, 0xFF, 64 * 4, stream);  // encoded +max

  int nb = (N + 1023) / 1024;  // 98 for N=100000 (<=128 required by k_scan2)
  k_count<<<1024, 256, 0, stream>>>(edge, E, N, cnt);
  k_scan1<<<nb, 1024, 0, stream>>>(cnt, N, incl, bsum);
  k_scan2<<<1, 128, 0, stream>>>(bsum, nb, boff);
  k_aux<<<(N + 256) / 256, 256, 0, stream>>>(cnt, incl, boff, N, E, row_ptr, cursor, dinv);
  k_fill<<<1024, 256, 0, stream>>>(edge, E, N, cursor, srcs);

  int gx = (N + 63) / 64;
  // layer 1: P = bf16((X @ W1)*dinv) ; H = relu(dinv*(P+gather) + b1)
  k_gemm<2><<<gx, 256, 0, stream>>>(X, W1, dinv, P, N);
  k_agg<128, 1><<<N, 128, 0, stream>>>(P, row_ptr, srcs, dinv, b1, H);
  // layer 2
  k_gemm<2><<<gx, 256, 0, stream>>>(H, W2, dinv, P, N);
  k_agg<128, 1><<<N, 128, 0, stream>>>(P, row_ptr, srcs, dinv, b2, H);
  // layer 3 (64 ch, no relu)
  k_gemm<1><<<gx, 256, 0, stream>>>(H, W3, dinv, P, N);
  k_agg<64, 0><<<N, 64, 0, stream>>>(P, row_ptr, srcs, dinv, b3, H);
  // min pool -> out[64]
  k_minpool<<<512, 256, 0, stream>>>(H, N, minenc);
  k_decode<<<1, 64, 0, stream>>>(minenc, out);
}

// Round 4
// 592.363 us; speedup vs baseline: 1.2246x; 1.0471x over previous
//
#include <hip/hip_runtime.h>
#include <stdint.h>
#include <stddef.h>

// ---------------- helpers ----------------
static __device__ __forceinline__ unsigned enc_min(float v) {
  unsigned u = __float_as_uint(v);
  return (u & 0x80000000u) ? ~u : (u | 0x80000000u);
}
static __device__ __forceinline__ unsigned short f2bf(float f) {
  unsigned u = __float_as_uint(f);
  u += 0x7fffu + ((u >> 16) & 1u);
  return (unsigned short)(u >> 16);
}

// ---------------- degree count, XCD-binned ----------------
__global__ void k_count(const int* __restrict__ edge, int E, int N, int* __restrict__ cnt) {
  int grp = blockIdx.x & 7;
  int bslot = blockIdx.x >> 3;
  int nslot = gridDim.x >> 3;
  int lo = (int)(((long long)N * grp) >> 3);
  int hi = (int)(((long long)N * (grp + 1)) >> 3);
  for (int e = bslot * blockDim.x + threadIdx.x; e < E; e += nslot * blockDim.x) {
    int d = edge[E + e];
    if (d >= lo && d < hi) atomicAdd(&cnt[d], 1);
  }
}

// ---------------- block inclusive scan (1024/block) ----------------
__global__ void k_scan1(const int* __restrict__ cnt, int N,
                        int* __restrict__ incl, int* __restrict__ bsum) {
  __shared__ int sm[1024];
  int tid = threadIdx.x;
  int i = blockIdx.x * 1024 + tid;
  int v = (i < N) ? cnt[i] : 0;
  sm[tid] = v;
  __syncthreads();
  for (int off = 1; off < 1024; off <<= 1) {
    int t = (tid >= off) ? sm[tid - off] : 0;
    __syncthreads();
    sm[tid] += t;
    __syncthreads();
  }
  if (i < N) incl[i] = sm[tid];
  if (tid == 1023) bsum[blockIdx.x] = sm[1023];
}

// ---------------- scan of block sums (nb <= 128) ----------------
__global__ void k_scan2(const int* __restrict__ bsum, int nb, int* __restrict__ boff) {
  __shared__ int sm[128];
  int tid = threadIdx.x;
  int v = (tid < nb) ? bsum[tid] : 0;
  sm[tid] = v;
  __syncthreads();
  for (int off = 1; off < 128; off <<= 1) {
    int t = (tid >= off) ? sm[tid - off] : 0;
    __syncthreads();
    sm[tid] += t;
    __syncthreads();
  }
  if (tid < nb) boff[tid] = sm[tid] - v;  // exclusive
}

// ---------------- row_ptr / cursor / dinv ----------------
__global__ void k_aux(const int* __restrict__ cnt, const int* __restrict__ incl,
                      const int* __restrict__ boff, int N, int E,
                      int* __restrict__ row_ptr, int* __restrict__ cursor,
                      float* __restrict__ dinv) {
  int i = blockIdx.x * blockDim.x + threadIdx.x;
  if (i < N) {
    int rp = incl[i] - cnt[i] + boff[i >> 10];
    row_ptr[i] = rp;
    cursor[i] = rp;
    dinv[i] = 1.0f / sqrtf((float)(cnt[i] + 1));  // +1 self-loop
  } else if (i == N) {
    row_ptr[N] = E;
  }
}

// ---------------- CSR fill (bucket by dst, store src), XCD-binned ----------------
__global__ void k_fill(const int* __restrict__ edge, int E, int N,
                       int* __restrict__ cursor, int* __restrict__ srcs) {
  int grp = blockIdx.x & 7;
  int bslot = blockIdx.x >> 3;
  int nslot = gridDim.x >> 3;
  int lo = (int)(((long long)N * grp) >> 3);
  int hi = (int)(((long long)N * (grp + 1)) >> 3);
  for (int e = bslot * blockDim.x + threadIdx.x; e < E; e += nslot * blockDim.x) {
    int d = edge[E + e];
    if (d >= lo && d < hi) {
      int s = edge[e];
      int pos = atomicAdd(&cursor[d], 1);
      srcs[pos] = s;
    }
  }
}

// ---------------- GEMM: P = bf16((A @ W) * dinv[row]), sliced layout ----------------
// P layout: slice s (16 channels) is contiguous: P[s*N*16 + row*16 + (ch&15)], bf16.
// block: 256 threads (16x16), tile 64 rows x (64*G) cols, K chunked by 32.
template <int G>
__global__ __launch_bounds__(256) void k_gemm(const float* __restrict__ A,
                                              const float* __restrict__ W,
                                              const float* __restrict__ dinv,
                                              unsigned short* __restrict__ P, int M) {
  const int K = 128;
  const int Nc = 64 * G;
  __shared__ float As[32][68];           // As[k][m], transposed A tile
  __shared__ float Bs[32][64 * G + 4];   // Bs[k][n]
  int tid = threadIdx.x;
  int tx = tid & 15, ty = tid >> 4;
  int m0 = blockIdx.x * 64;
  float acc[G][4][4];
#pragma unroll
  for (int g = 0; g < G; ++g)
#pragma unroll
    for (int i = 0; i < 4; ++i)
#pragma unroll
      for (int j = 0; j < 4; ++j) acc[g][i][j] = 0.f;

  for (int kc = 0; kc < K; kc += 32) {
#pragma unroll
    for (int q = 0; q < 2; ++q) {
      int f = q * 256 + tid;  // 0..511 -> 64 rows x 8 float4
      int m = f >> 3, k4 = f & 7;
      int row = m0 + m;
      if (row >= M) row = M - 1;  // clamp; garbage rows never stored
      float4 v = *(const float4*)&A[(size_t)row * K + kc + k4 * 4];
      As[k4 * 4 + 0][m] = v.x;
      As[k4 * 4 + 1][m] = v.y;
      As[k4 * 4 + 2][m] = v.z;
      As[k4 * 4 + 3][m] = v.w;
    }
#pragma unroll
    for (int q = 0; q < 2 * G; ++q) {
      int f = q * 256 + tid;  // 32 rows x 16G float4
      int kk = f / (16 * G), n4 = f % (16 * G);
      float4 v = *(const float4*)&W[(size_t)(kc + kk) * Nc + n4 * 4];
      *(float4*)&Bs[kk][n4 * 4] = v;
    }
    __syncthreads();
#pragma unroll
    for (int k = 0; k < 32; ++k) {
      float4 a4 = *(const float4*)&As[k][ty * 4];
      float av[4] = {a4.x, a4.y, a4.z, a4.w};
#pragma unroll
      for (int g = 0; g < G; ++g) {
        float4 b4 = *(const float4*)&Bs[k][g * 64 + tx * 4];
        float bv[4] = {b4.x, b4.y, b4.z, b4.w};
#pragma unroll
        for (int i = 0; i < 4; ++i)
#pragma unroll
          for (int j = 0; j < 4; ++j) acc[g][i][j] = fmaf(av[i], bv[j], acc[g][i][j]);
      }
    }
    __syncthreads();
  }
#pragma unroll
  for (int i = 0; i < 4; ++i) {
    int row = m0 + ty * 4 + i;
    if (row < M) {
      float dv = dinv[row];
#pragma unroll
      for (int g = 0; g < G; ++g) {
        int col = g * 64 + tx * 4;        // 4 consecutive channels, same 16-ch slice
        int s = col >> 4, u = col & 15;
        uint2 o;
        o.x = (unsigned)f2bf(acc[g][i][0] * dv) | ((unsigned)f2bf(acc[g][i][1] * dv) << 16);
        o.y = (unsigned)f2bf(acc[g][i][2] * dv) | ((unsigned)f2bf(acc[g][i][3] * dv) << 16);
        *(uint2*)&P[(size_t)s * M * 16 + (size_t)row * 16 + u] = o;
      }
    }
  }
}

// ---------------- sliced aggregation ----------------
// grid = ceil(N/32) * NS; blockIdx % NS = slice. With blockIdx%8 -> XCD, each
// slice's 3.2 MB P region stays resident in one XCD's L2 (pair for NS=4).
// Block: 256 threads = 4 waves; wave covers 8 nodes x 8 ushort2-lanes (16 ch).
// Edge lists of the 32 consecutive nodes are contiguous in CSR -> coalesced
// LDS staging; per-lane inner loop gathers 32 B per (neighbor, node).
template <int C, int RELU>
__global__ __launch_bounds__(256) void k_agg2(const unsigned short* __restrict__ P,
                                              const int* __restrict__ row_ptr,
                                              const int* __restrict__ srcs,
                                              const float* __restrict__ dinv,
                                              const float* __restrict__ bias,
                                              float* __restrict__ Hout, int N) {
  const int NS = C / 16;
  const int CAP = 768;  // mean edges per 32-node group = 512, sigma ~23
  __shared__ int s_idx[CAP];
  __shared__ int s_rp[33];
  int tid = threadIdx.x;
  int grp = blockIdx.x / NS;
  int s = blockIdx.x % NS;
  const unsigned short* Ps = P + (size_t)s * N * 16;

  int base = grp * 32;
  if (tid < 33) {
    int node = base + tid;
    s_rp[tid] = row_ptr[node < N ? node : N];
  }
  __syncthreads();
  int e0 = s_rp[0], e1 = s_rp[32];

  int wv = tid >> 6, lane = tid & 63;
  int nb = wv * 8 + (lane >> 3);  // node-in-block 0..31
  int cp = lane & 7;              // channel pair 0..7 within slice
  int d = base + nb;
  bool valid = d < N;
  int lo_n = s_rp[nb], hi_n = s_rp[nb + 1];

  float a0 = 0.f, a1 = 0.f;
  if (valid) {  // self-loop term
    unsigned v = *(const unsigned*)&Ps[(size_t)d * 16 + cp * 2];
    a0 = __uint_as_float(v << 16);
    a1 = __uint_as_float(v & 0xffff0000u);
  }

  for (int w0 = e0; w0 < e1; w0 += CAP) {
    int wend = min(w0 + CAP, e1);
    int cnt = wend - w0;
    __syncthreads();
    for (int t = tid; t < cnt; t += 256) s_idx[t] = srcs[w0 + t];
    __syncthreads();
    int lo = max(lo_n, w0), hi = min(hi_n, wend);
    int j = lo;
    for (; j + 4 <= hi; j += 4) {
      int i0 = s_idx[j - w0 + 0], i1 = s_idx[j - w0 + 1];
      int i2 = s_idx[j - w0 + 2], i3 = s_idx[j - w0 + 3];
      unsigned v0 = *(const unsigned*)&Ps[(size_t)i0 * 16 + cp * 2];
      unsigned v1 = *(const unsigned*)&Ps[(size_t)i1 * 16 + cp * 2];
      unsigned v2 = *(const unsigned*)&Ps[(size_t)i2 * 16 + cp * 2];
      unsigned v3 = *(const unsigned*)&Ps[(size_t)i3 * 16 + cp * 2];
      a0 += __uint_as_float(v0 << 16); a1 += __uint_as_float(v0 & 0xffff0000u);
      a0 += __uint_as_float(v1 << 16); a1 += __uint_as_float(v1 & 0xffff0000u);
      a0 += __uint_as_float(v2 << 16); a1 += __uint_as_float(v2 & 0xffff0000u);
      a0 += __uint_as_float(v3 << 16); a1 += __uint_as_float(v3 & 0xffff0000u);
    }
    for (; j < hi; ++j) {
      int i0 = s_idx[j - w0];
      unsigned v0 = *(const unsigned*)&Ps[(size_t)i0 * 16 + cp * 2];
      a0 += __uint_as_float(v0 << 16);
      a1 += __uint_as_float(v0 & 0xffff0000u);
    }
  }

  if (valid) {
    int c = s * 16 + cp * 2;
    float dv = dinv[d];
    float h0 = dv * a0 + bias[c];
    float h1 = dv * a1 + bias[c + 1];
    if (RELU) { h0 = fmaxf(h0, 0.f); h1 = fmaxf(h1, 0.f); }
    *(float2*)&Hout[(size_t)d * C + c] = make_float2(h0, h1);
  }
}

// ---------------- min pool over nodes ----------------
__global__ void k_minpool(const float* __restrict__ H, int N, unsigned* __restrict__ minenc) {
  __shared__ float sm[256];
  int tid = threadIdx.x;
  int c = tid & 63;
  int r = (blockIdx.x * blockDim.x + tid) >> 6;
  int stride = (gridDim.x * blockDim.x) >> 6;
  float mn = 3.402823466e38f;
  for (; r < N; r += stride) mn = fminf(mn, H[(size_t)r * 64 + c]);
  sm[tid] = mn;
  __syncthreads();
  if (tid < 64) {
    mn = fminf(fminf(sm[tid], sm[tid + 64]), fminf(sm[tid + 128], sm[tid + 192]));
    atomicMin(&minenc[c], enc_min(mn));
  }
}

__global__ void k_decode(const unsigned* __restrict__ minenc, float* __restrict__ out) {
  int c = threadIdx.x;
  unsigned k = minenc[c];
  unsigned u = (k & 0x80000000u) ? (k & 0x7FFFFFFFu) : ~k;
  out[c] = __uint_as_float(u);
}

// ---------------- launch ----------------
extern "C" void kernel_launch(void* const* d_in, const int* in_sizes, int n_in,
                              void* d_out, int out_size, void* d_ws, size_t ws_size,
                              hipStream_t stream) {
  const float* X  = (const float*)d_in[0];
  const int* edge = (const int*)d_in[1];
  const float* W1 = (const float*)d_in[2];
  const float* b1 = (const float*)d_in[3];
  const float* W2 = (const float*)d_in[4];
  const float* b2 = (const float*)d_in[5];
  const float* W3 = (const float*)d_in[6];
  const float* b3 = (const float*)d_in[7];
  float* out = (float*)d_out;

  const int IN_CH = 128;
  int N = in_sizes[0] / IN_CH;
  int E = in_sizes[1] / 2;

  char* ws = (char*)d_ws;
  size_t off = 0;
  auto alloc = [&](size_t bytes) {
    void* p = ws + off;
    off = (off + bytes + 255) & ~(size_t)255;
    return p;
  };
  unsigned short* P = (unsigned short*)alloc((size_t)N * 128 * 2);  // 25.6 MB bf16, sliced
  float* H       = (float*)alloc((size_t)N * 128 * 4);              // 51.2 MB
  int* srcs      = (int*)alloc((size_t)E * 4);                      // 6.4 MB
  int* cnt       = (int*)alloc((size_t)N * 4);
  int* incl      = (int*)alloc((size_t)N * 4);
  int* row_ptr   = (int*)alloc((size_t)(N + 1) * 4);
  int* cursor    = (int*)alloc((size_t)N * 4);
  float* dinv    = (float*)alloc((size_t)N * 4);
  int* bsum      = (int*)alloc(1024);
  int* boff      = (int*)alloc(1024);
  unsigned* minenc = (unsigned*)alloc(256);

  hipMemsetAsync(cnt, 0, (size_t)N * 4, stream);
  hipMemsetAsync(minenc, 0xFF, 64 * 4, stream);  // encoded +max

  int nb = (N + 1023) / 1024;  // 98 for N=100000 (<=128 required by k_scan2)
  k_count<<<1024, 256, 0, stream>>>(edge, E, N, cnt);
  k_scan1<<<nb, 1024, 0, stream>>>(cnt, N, incl, bsum);
  k_scan2<<<1, 128, 0, stream>>>(bsum, nb, boff);
  k_aux<<<(N + 256) / 256, 256, 0, stream>>>(cnt, incl, boff, N, E, row_ptr, cursor, dinv);
  k_fill<<<1024, 256, 0, stream>>>(edge, E, N, cursor, srcs);

  int gx = (N + 63) / 64;
  int groups = (N + 31) / 32;
  // layer 1
  k_gemm<2><<<gx, 256, 0, stream>>>(X, W1, dinv, P, N);
  k_agg2<128, 1><<<groups * 8, 256, 0, stream>>>(P, row_ptr, srcs, dinv, b1, H, N);
  // layer 2
  k_gemm<2><<<gx, 256, 0, stream>>>(H, W2, dinv, P, N);
  k_agg2<128, 1><<<groups * 8, 256, 0, stream>>>(P, row_ptr, srcs, dinv, b2, H, N);
  // layer 3 (64 ch, no relu)
  k_gemm<1><<<gx, 256, 0, stream>>>(H, W3, dinv, P, N);
  k_agg2<64, 0><<<groups * 4, 256, 0, stream>>>(P, row_ptr, srcs, dinv, b3, H, N);
  // min pool -> out[64]
  k_minpool<<<512, 256, 0, stream>>>(H, N, minenc);
  k_decode<<<1, 64, 0, stream>>>(minenc, out);
}